// Round 9
// baseline (430.492 us; speedup 1.0000x reference)
//
#include <hip/hip_runtime.h>
#include <hip/hip_bf16.h>
#include <cstdint>
#include <cstddef>

typedef unsigned short u16;
typedef __attribute__((ext_vector_type(8))) __bf16 bf16x8;
typedef __attribute__((ext_vector_type(4))) float f32x4;

__device__ __forceinline__ u16 f2b(float f) {
  __hip_bfloat16 h = __float2bfloat16(f);
  return *reinterpret_cast<u16*>(&h);
}
__device__ __forceinline__ uint32_t pk2(float a, float b) {
  __hip_bfloat162 h = __float22bfloat162_rn(make_float2(a, b));
  return *reinterpret_cast<uint32_t*>(&h);
}
__device__ __forceinline__ float b2f(u16 u) {
  union { float f; uint32_t i; } x; x.i = ((uint32_t)u) << 16; return x.f;
}
__device__ __forceinline__ f32x4 mfma16(bf16x8 a, bf16x8 b, f32x4 c) {
  return __builtin_amdgcn_mfma_f32_16x16x32_bf16(a, b, c, 0, 0, 0);
}
__device__ __forceinline__ void async16(const void* g, void* l) {
  __builtin_amdgcn_global_load_lds((const __attribute__((address_space(1))) uint32_t*)g,
                                   (__attribute__((address_space(3))) uint32_t*)l, 16, 0, 0);
}

// ---------------------------------------------------------------------------
// fc_w1 (256x8000) permuted to the conv-epilogue k-order:
// x element k' = t*32 + c'  with  c2 = ((c'>>2)&1)*16 + (c'>>3)*4 + (c'&3)
__global__ __launch_bounds__(256) void w1_perm(const float* __restrict__ w,
                                               u16* __restrict__ o) {
  __shared__ float L[8000];
  int j = blockIdx.x, tid = threadIdx.x;
  for (int i = tid; i < 8000; i += 256) L[i] = w[(size_t)j * 8000 + i];
  __syncthreads();
  for (int i = tid; i < 8000; i += 256) {
    int tt = i >> 5, cc = i & 31;
    int c2 = ((cc >> 2) & 1) * 16 + (cc >> 3) * 4 + (cc & 3);
    o[(size_t)j * 8000 + i] = f2b(L[c2 * 250 + tt]);
  }
}

struct CvtArgs {
  const float* src[13];
  void* dst[13];
  int cum[14];
  int kind[13];  // 0=f2b copy, 1=w2 permute, 2=w1 zero-pad, 3=float copy
};
__global__ __launch_bounds__(256) void f2b_multi(CvtArgs a, float* stats) {
  int i = blockIdx.x * 256 + threadIdx.x;
  if (blockIdx.x == 0 && threadIdx.x < 128) stats[threadIdx.x] = 0.f;
  int seg = 0;
  #pragma unroll
  for (int s = 1; s < 13; ++s) if (i >= a.cum[s]) seg = s;
  if (i < a.cum[13]) {
    int off = i - a.cum[seg];
    int kind = a.kind[seg];
    const float* src = a.src[seg];
    if (kind == 0) {
      ((u16*)a.dst[seg])[off] = f2b(src[off]);
    } else if (kind == 1) {
      int c2 = off / 96, rem = off - c2 * 96, kk = rem >> 5, c1 = rem & 31;
      ((u16*)a.dst[seg])[off] = f2b(src[(c2 * 32 + c1) * 3 + kk]);
    } else if (kind == 2) {
      int c1 = off >> 5, k = off & 31;
      ((u16*)a.dst[seg])[off] = f2b(k < 5 ? src[c1 * 5 + k] : 0.f);
    } else {
      ((float*)a.dst[seg])[off] = src[off];
    }
  }
}

// ---------------------------------------------------------------------------
// MEGA: fused conv1+conv2+fc1 for 64 scan rows per block, 512 threads.
// Waves 0-3: conv (16 rows each, h1 ring in private LDS, x-chunk to shared
// double-buffered LDS). All 8 waves: fc1 GEMM vs async-staged w1 chunks.
// Output: hb[row][256] = relu(x.w1^T + b1) in bf16 (FULL K=8000, no split).
__global__ __launch_bounds__(512) void mega(
    const float* __restrict__ scan, const u16* __restrict__ w1g,
    const float* __restrict__ cb1, const u16* __restrict__ w2g,
    const float* __restrict__ cb2, const u16* __restrict__ w1b,
    const float* __restrict__ fb1, u16* __restrict__ hb) {
  __shared__ __align__(16) u16 Ws[2][256 * 32];  // w1 chunk [n][4 xor-slots*8]
  __shared__ __align__(16) u16 Xs[2][64 * 40];   // x chunk [row][32], stride 40
  __shared__ __align__(16) u16 h1w[4][16 * 136]; // per conv-wave h1 ring
  int tid = threadIdx.x, lane = tid & 63, wv = tid >> 6;
  int l15 = lane & 15, quad = lane >> 4;
  int r0 = blockIdx.x * 64;
  f32x4 zero = {0.f, 0.f, 0.f, 0.f};
  // fc1: n-split 8 waves x 32
  int wn = wv * 32;
  f32x4 acc[4][2];
  #pragma unroll
  for (int i = 0; i < 4; ++i) { acc[i][0] = zero; acc[i][1] = zero; }
  // w1 staging descriptors (1024 chunks of 16B, 2 per thread)
  size_t wsrc[2]; int wdst[2];
  #pragma unroll
  for (int it = 0; it < 2; ++it) {
    int c = it * 512 + tid;
    int n = c >> 2, sl = c & 3;
    int ks = sl ^ ((n >> 1) & 3);
    wsrc[it] = (size_t)n * 8000 + ks * 8;
    wdst[it] = c * 8;
  }
  int woff[2];
  #pragma unroll
  for (int j = 0; j < 2; ++j) {
    int nj = wn + j * 16 + l15;
    int sj = quad ^ ((nj >> 1) & 3);
    woff[j] = nj * 32 + sj * 8;
  }
  int xoff[4];
  #pragma unroll
  for (int i = 0; i < 4; ++i) xoff[i] = (i * 16 + l15) * 40 + quad * 8;

  // conv setup (waves 0-3 own rows wv*16 + l15)
  bool cw = wv < 4;
  const float* srow = scan + (size_t)(r0 + (wv & 3) * 16 + l15) * 256;
  u16* myh1 = &h1w[wv & 3][0];
  int h1wo = l15 * 136 + quad * 4;   // + slot*32 + mt*16
  int h1ro = l15 * 136 + quad * 8;   // + slot*32
  int xwo = ((wv & 3) * 16 + l15) * 40 + quad * 8;
  bf16x8 w1f[2], w2f[2][3];
  float cb1v[2][4], cb2v[2][4];
  if (cw) {
    w1f[0] = *(const bf16x8*)&w1g[l15 * 32 + quad * 8];
    w1f[1] = *(const bf16x8*)&w1g[(16 + l15) * 32 + quad * 8];
    #pragma unroll
    for (int i = 0; i < 2; ++i)
      #pragma unroll
      for (int kk = 0; kk < 3; ++kk)
        w2f[i][kk] = *(const bf16x8*)&w2g[(i * 16 + l15) * 96 + kk * 32 + quad * 8];
    #pragma unroll
    for (int i = 0; i < 2; ++i)
      #pragma unroll
      for (int r = 0; r < 4; ++r) {
        cb1v[i][r] = cb1[i * 16 + quad * 4 + r];
        cb2v[i][r] = cb2[i * 16 + quad * 4 + r];
      }
  }
  float sreg[5] = {0.f, 0.f, 0.f, 0.f, 0.f};

  auto conv1_step = [&](int slot) {
    union { bf16x8 v; uint32_t d[4]; } u;
    uint32_t d0 = pk2(sreg[0], sreg[1]);
    uint32_t d1 = pk2(sreg[2], sreg[3]);
    uint32_t d2 = pk2(sreg[4], 0.f);
    u.d[0] = (quad == 0) ? d0 : 0u;
    u.d[1] = (quad == 0) ? d1 : 0u;
    u.d[2] = (quad == 0) ? d2 : 0u;
    u.d[3] = 0u;
    f32x4 a0 = mfma16(w1f[0], u.v, zero);
    f32x4 a1 = mfma16(w1f[1], u.v, zero);
    #pragma unroll
    for (int mt = 0; mt < 2; ++mt) {
      f32x4 a = mt ? a1 : a0;
      float v0 = fmaxf(a[0] + cb1v[mt][0], 0.f);
      float v1 = fmaxf(a[1] + cb1v[mt][1], 0.f);
      float v2 = fmaxf(a[2] + cb1v[mt][2], 0.f);
      float v3 = fmaxf(a[3] + cb1v[mt][3], 0.f);
      uint2 w; w.x = pk2(v0, v1); w.y = pk2(v2, v3);
      *(uint2*)&myh1[h1wo + slot * 32 + mt * 16] = w;
    }
  };

  // prologue: stage-0 w1 + first two h1 columns
  #pragma unroll
  for (int it = 0; it < 2; ++it)
    async16(w1b + wsrc[it], &Ws[0][wdst[it]]);
  if (cw) {
    if (quad == 0) {
      #pragma unroll
      for (int k = 0; k < 5; ++k) sreg[k] = srow[k];
    }
    conv1_step(0);
    if (quad == 0) {
      sreg[0] = sreg[1]; sreg[1] = sreg[2]; sreg[2] = sreg[3]; sreg[3] = sreg[4];
      sreg[4] = srow[5];
    }
    conv1_step(1);
    if (quad == 0) {
      sreg[0] = sreg[1]; sreg[1] = sreg[2]; sreg[2] = sreg[3]; sreg[3] = sreg[4];
      sreg[4] = srow[6];
    }
  }

  #pragma unroll 1
  for (int t = 0; t < 250; ++t) {
    int buf = t & 1;
    if (cw) {
      conv1_step((t + 2) & 3);  // uses sreg = s[t+2 .. t+6]
      if (quad == 0) {
        sreg[0] = sreg[1]; sreg[1] = sreg[2]; sreg[2] = sreg[3]; sreg[3] = sreg[4];
        if (t < 249) sreg[4] = srow[t + 7];
      }
      // conv2 for t
      f32x4 c0 = zero, c1 = zero;
      #pragma unroll
      for (int kk = 0; kk < 3; ++kk) {
        int slot = (t + kk) & 3;
        bf16x8 h = *(const bf16x8*)&myh1[h1ro + slot * 32];
        c0 = mfma16(w2f[0][kk], h, c0);
        c1 = mfma16(w2f[1][kk], h, c1);
      }
      union { bf16x8 v; uint32_t d[4]; } o;
      {
        float v0 = fmaxf(c0[0] + cb2v[0][0], 0.f);
        float v1 = fmaxf(c0[1] + cb2v[0][1], 0.f);
        float v2 = fmaxf(c0[2] + cb2v[0][2], 0.f);
        float v3 = fmaxf(c0[3] + cb2v[0][3], 0.f);
        o.d[0] = pk2(v0, v1); o.d[1] = pk2(v2, v3);
        float w0 = fmaxf(c1[0] + cb2v[1][0], 0.f);
        float w1 = fmaxf(c1[1] + cb2v[1][1], 0.f);
        float w2 = fmaxf(c1[2] + cb2v[1][2], 0.f);
        float w3 = fmaxf(c1[3] + cb2v[1][3], 0.f);
        o.d[2] = pk2(w0, w1); o.d[3] = pk2(w2, w3);
      }
      *(bf16x8*)&Xs[buf][xwo] = o.v;
    }
    __syncthreads();  // publish Xs[buf]; drain Ws[buf] staging
    if (t < 249) {    // prefetch next w1 chunk into the other buffer
      int kb = (t + 1) * 32;
      u16* Wd = &Ws[(t + 1) & 1][0];
      #pragma unroll
      for (int it = 0; it < 2; ++it)
        async16(w1b + wsrc[it] + kb, Wd + wdst[it]);
    }
    const u16* Wb = &Ws[buf][0];
    const u16* Xb = &Xs[buf][0];
    bf16x8 bw0 = *(const bf16x8*)&Wb[woff[0]];
    bf16x8 bw1 = *(const bf16x8*)&Wb[woff[1]];
    #pragma unroll
    for (int i = 0; i < 4; ++i) {
      bf16x8 bx = *(const bf16x8*)&Xb[xoff[i]];
      acc[i][0] = mfma16(bx, bw0, acc[i][0]);
      acc[i][1] = mfma16(bx, bw1, acc[i][1]);
    }
  }
  // epilogue: h = relu(acc + b1) -> bf16
  float b1v[2];
  b1v[0] = fb1[wn + l15];
  b1v[1] = fb1[wn + 16 + l15];
  #pragma unroll
  for (int i = 0; i < 4; ++i) {
    int row = r0 + i * 16 + quad * 4;
    #pragma unroll
    for (int j = 0; j < 2; ++j) {
      int n = wn + j * 16 + l15;
      #pragma unroll
      for (int r = 0; r < 4; ++r) {
        float v = fmaxf(acc[i][j][r] + b1v[j], 0.f);
        hb[(size_t)(row + r) * 256 + n] = f2b(v);
      }
    }
  }
}

// ---------------------------------------------------------------------------
// NT bf16 MFMA GEMM, MROWS x 128 tile, BK=64, dbuf + depth-1 prefetch,
// 8-slot XOR swizzle. MODE 1: +bias relu bf16. MODE 4: merged KVQ.
template <int MODE, int MROWS>
__global__ __launch_bounds__(256) void gemm_bt(
    const u16* __restrict__ A, int lda, const u16* __restrict__ W, int ldw,
    const float* __restrict__ bias, float* __restrict__ outF,
    u16* __restrict__ outB, int ldo, int nst, int a_sel, size_t out_zoff) {
  constexpr int AI = (MROWS * 8) / 256;
  __shared__ __align__(16) u16 As[2][MROWS * 64];
  __shared__ __align__(16) u16 Bs[2][128 * 64];
  int tid = threadIdx.x;
  int m0 = blockIdx.y * MROWS;
  int sel = (MODE == 4) ? blockIdx.x : 0;
  int n0 = (MODE == 4) ? 0 : blockIdx.x * 128;
  if (MODE == 4) {
    size_t woff = (sel < 2) ? (size_t)sel * 128 : (size_t)(256 + (m0 >> 12) * 128);
    W += woff * 128;
    outB += (size_t)sel * 12288 * 128;
  }
  if (a_sel) A += (size_t)(blockIdx.x >> 1) * a_sel;
  int kbase = blockIdx.z * nst * 64;
  if (MODE == 0) outF += (size_t)blockIdx.z * out_zoff;
  const u16* Ap = A + (size_t)m0 * lda + kbase;
  const u16* Wp = W + (size_t)n0 * ldw + kbase;
  int lane = tid & 63, wv = tid >> 6;
  int l15 = lane & 15, quad = lane >> 4;
  int wm = (wv >> 1) * (MROWS / 2), wn = (wv & 1) * 64;
  constexpr int MI = MROWS / 32;
  f32x4 zero = {0.f, 0.f, 0.f, 0.f};
  f32x4 acc[MI][4];
  #pragma unroll
  for (int i = 0; i < MI; ++i)
    #pragma unroll
    for (int j = 0; j < 4; ++j) acc[i][j] = zero;

  int sraA[AI], sofA[AI], sdsA[AI];
  #pragma unroll
  for (int it = 0; it < AI; ++it) {
    int c = it * 256 + tid;
    int row = c >> 3, slot = c & 7;
    sraA[it] = row;
    sofA[it] = ((slot ^ (row & 7)) * 8);
    sdsA[it] = c * 8;
  }
  int sraW[4], sofW[4], sdsW[4];
  #pragma unroll
  for (int it = 0; it < 4; ++it) {
    int c = it * 256 + tid;
    int row = c >> 3, slot = c & 7;
    sraW[it] = row;
    sofW[it] = ((slot ^ (row & 7)) * 8);
    sdsW[it] = c * 8;
  }
  int rslot[2];
  rslot[0] = ((quad ^ (l15 & 7)) * 8);
  rslot[1] = (((4 + quad) ^ (l15 & 7)) * 8);

  #pragma unroll 1
  for (int st = 0; st < nst; ++st) {
    if (st == 0) {
      #pragma unroll
      for (int it = 0; it < AI; ++it)
        async16(Ap + (size_t)sraA[it] * lda + sofA[it], &As[0][sdsA[it]]);
      #pragma unroll
      for (int it = 0; it < 4; ++it)
        async16(Wp + (size_t)sraW[it] * ldw + sofW[it], &Bs[0][sdsW[it]]);
    }
    __syncthreads();
    if (st + 1 < nst) {
      const u16* An = Ap + (st + 1) * 64;
      const u16* Wn = Wp + (st + 1) * 64;
      u16* Ad = &As[(st + 1) & 1][0];
      u16* Bd = &Bs[(st + 1) & 1][0];
      #pragma unroll
      for (int it = 0; it < AI; ++it)
        async16(An + (size_t)sraA[it] * lda + sofA[it], Ad + sdsA[it]);
      #pragma unroll
      for (int it = 0; it < 4; ++it)
        async16(Wn + (size_t)sraW[it] * ldw + sofW[it], Bd + sdsW[it]);
    }
    const u16* Ab = &As[st & 1][0];
    const u16* Bb = &Bs[st & 1][0];
    #pragma unroll
    for (int s = 0; s < 2; ++s) {
      bf16x8 af[MI], bfr[4];
      #pragma unroll
      for (int i = 0; i < MI; ++i)
        af[i] = *(const bf16x8*)&Ab[(wm + i * 16 + l15) * 64 + rslot[s]];
      #pragma unroll
      for (int j = 0; j < 4; ++j)
        bfr[j] = *(const bf16x8*)&Bb[(wn + j * 16 + l15) * 64 + rslot[s]];
      #pragma unroll
      for (int i = 0; i < MI; ++i)
        #pragma unroll
        for (int j = 0; j < 4; ++j) acc[i][j] = mfma16(af[i], bfr[j], acc[i][j]);
    }
  }
  #pragma unroll
  for (int i = 0; i < MI; ++i) {
    int mb = m0 + wm + i * 16 + quad * 4;
    #pragma unroll
    for (int j = 0; j < 4; ++j) {
      int n = n0 + wn + j * 16 + l15;
      float bv_ = (MODE == 1 || MODE == 4) ? bias[n] : 0.f;
      #pragma unroll
      for (int r = 0; r < 4; ++r) {
        float v = acc[i][j][r];
        if (MODE == 0) {
          outF[(size_t)(mb + r) * ldo + n] = v;
        } else if (MODE == 1) {
          v = fmaxf(v + bv_, 0.f);
          outB[(size_t)(mb + r) * ldo + n] = f2b(v);
        } else {
          if (sel == 1) { v += bv_; v = v >= 0.f ? v : 0.01f * v; }
          outB[(size_t)(mb + r) * ldo + n] = f2b(v);
        }
      }
    }
  }
}

// ---------------------------------------------------------------------------
// fc2 on precomputed h (bf16, relu+b1 applied) + inps rows + stat partials
__global__ __launch_bounds__(256) void fc2_stats(
    const u16* __restrict__ hb, const float* __restrict__ w2,
    const float* __restrict__ b2, const float* __restrict__ obs,
    const float* __restrict__ acts, float* __restrict__ inps,
    float* __restrict__ stats) {
  __shared__ float hL[32 * 260];
  __shared__ float w2L[10 * 260];
  __shared__ float ipL[32 * 61];
  int tid = threadIdx.x, r0 = blockIdx.x * 32;
  for (int i = tid; i < 2560; i += 256) w2L[(i >> 8) * 260 + (i & 255)] = w2[i];
  for (int i = tid; i < 32 * 48; i += 256) {
    int r = i / 48, f = i - r * 48;
    ipL[r * 61 + f] = obs[(size_t)(r0 + r) * 48 + f];
  }
  if (tid < 64) {
    int r = tid >> 1, f = tid & 1;
    ipL[r * 61 + 48 + f] = acts[(size_t)(r0 + r) * 2 + f];
  }
  for (int i = tid; i < 1024; i += 256) {  // 32 rows x 32 vec8
    int r = i >> 5, cv = (i & 31) * 8;
    const u16* hp = &hb[(size_t)(r0 + r) * 256 + cv];
    #pragma unroll
    for (int e = 0; e < 8; ++e) hL[r * 260 + cv + e] = b2f(hp[e]);
  }
  __syncthreads();
  {
    int r = tid >> 3, ob = tid & 7;
    for (int o = ob; o < 10; o += 8) {
      float a = 0.f;
      #pragma unroll 8
      for (int c = 0; c < 256; ++c) a += hL[r * 260 + c] * w2L[o * 260 + c];
      ipL[r * 61 + 50 + o] = a + b2[o];
    }
  }
  __syncthreads();
  for (int i = tid; i < 32 * 60; i += 256) {
    int r = i / 60, f = i - r * 60;
    inps[(size_t)(r0 + r) * 64 + f] = ipL[r * 61 + f];
  }
  if (tid < 60) {
    float s = 0.f, s2 = 0.f;
    for (int r = 0; r < 32; ++r) {
      float v = ipL[r * 61 + tid];
      s += v; s2 += v * v;
    }
    atomicAdd(&stats[tid], s);
    atomicAdd(&stats[64 + tid], s2);
  }
}

// ---------------------------------------------------------------------------
// normalize + enc (60->128) + leaky -> sa (bf16)
__global__ __launch_bounds__(256) void enc_kernel(
    const float* __restrict__ inps, const float* __restrict__ stats,
    const float* __restrict__ enc_w, const float* __restrict__ enc_b,
    u16* __restrict__ sab) {
  __shared__ float ewL[128 * 61];
  __shared__ float nrm[32 * 61];
  __shared__ float ebL[128];
  __shared__ float muL[60], ivL[60];
  int tid = threadIdx.x, r0 = blockIdx.x * 32;
  if (tid < 128) ebL[tid] = enc_b[tid];
  if (tid < 60) {
    float s = stats[tid], s2 = stats[64 + tid];
    float mu = s * (1.f / 12288.f);
    float var = s2 * (1.f / 12288.f) - mu * mu;
    muL[tid] = mu;
    ivL[tid] = rsqrtf(var + 1e-5f);
  }
  for (int i = tid; i < 128 * 60; i += 256) {
    int h = i / 60, f = i - h * 60;
    ewL[h * 61 + f] = enc_w[i];
  }
  __syncthreads();
  for (int i = tid; i < 32 * 60; i += 256) {
    int r = i / 60, f = i - r * 60;
    nrm[r * 61 + f] = (inps[(size_t)(r0 + r) * 64 + f] - muL[f]) * ivL[f];
  }
  __syncthreads();
  for (int i = tid; i < 32 * 128; i += 256) {
    int r = i >> 7, h = i & 127;
    float a = ebL[h];
    #pragma unroll 4
    for (int f = 0; f < 60; ++f) a += nrm[r * 61 + f] * ewL[h * 61 + f];
    a = a >= 0.f ? a : 0.01f * a;
    sab[(size_t)(r0 + r) * 128 + h] = f2b(a);
  }
}

// ---------------------------------------------------------------------------
// attention combine + emb = [sa | other] (bf16)
__global__ __launch_bounds__(128) void attn_combine(
    const u16* __restrict__ qb, const u16* __restrict__ keysb,
    const u16* __restrict__ valsb, const u16* __restrict__ sab,
    u16* __restrict__ emb) {
  __shared__ float qL[3][128], kL[3][128], vL[3][128];
  __shared__ float lg[3][8][3], wgt[3][8][3];
  int b = blockIdx.x, t = threadIdx.x;
  #pragma unroll
  for (int o = 0; o < 3; ++o) {
    size_t base = (size_t)(o * 4096 + b) * 128 + t;
    qL[o][t] = b2f(qb[base]);
    kL[o][t] = b2f(keysb[base]);
    vL[o][t] = b2f(valsb[base]);
  }
  __syncthreads();
  if (t < 72) {
    int g = t / 24, n = (t / 3) % 8, o = t % 3;
    float a = 0.f;
    #pragma unroll
    for (int d = 0; d < 16; ++d) a += qL[g][n * 16 + d] * kL[o][n * 16 + d];
    lg[g][n][o] = (o == g) ? -1e30f : a * 0.25f;
  }
  __syncthreads();
  if (t < 24) {
    int g = t / 8, n = t % 8;
    float m = fmaxf(fmaxf(lg[g][n][0], lg[g][n][1]), lg[g][n][2]);
    float e0 = expf(lg[g][n][0] - m), e1 = expf(lg[g][n][1] - m),
          e2 = expf(lg[g][n][2] - m);
    float inv = 1.f / (e0 + e1 + e2);
    wgt[g][n][0] = e0 * inv; wgt[g][n][1] = e1 * inv; wgt[g][n][2] = e2 * inv;
  }
  __syncthreads();
  int n = t >> 4, d = t & 15;
  #pragma unroll
  for (int g = 0; g < 3; ++g) {
    float o_ = wgt[g][n][0] * vL[0][n * 16 + d] +
               wgt[g][n][1] * vL[1][n * 16 + d] +
               wgt[g][n][2] * vL[2][n * 16 + d];
    size_t rbase = (size_t)(g * 4096 + b) * 256;
    emb[rbase + 128 + t] = f2b(o_);
    emb[rbase + t] = sab[(size_t)(g * 4096 + b) * 128 + t];
  }
}

// ---------------------------------------------------------------------------
// final layer on combined t2ab (stride 512)
__global__ __launch_bounds__(256) void final_dot(
    const u16* __restrict__ t2ab, const float* __restrict__ w3a,
    const float* __restrict__ b3a, const float* __restrict__ w3b,
    const float* __restrict__ b3b, float* __restrict__ out) {
  int wv = threadIdx.x >> 6, lane = threadIdx.x & 63;
  int row = blockIdx.x * 4 + wv;
  float sa_ = 0.f, sb_ = 0.f;
  #pragma unroll
  for (int e = 0; e < 4; ++e) {
    int c = lane * 4 + e;
    sa_ += b2f(t2ab[(size_t)row * 512 + c]) * w3a[c];
    sb_ += b2f(t2ab[(size_t)row * 512 + 256 + c]) * w3b[c];
  }
  #pragma unroll
  for (int off = 32; off; off >>= 1) {
    sa_ += __shfl_down(sa_, off);
    sb_ += __shfl_down(sb_, off);
  }
  if (lane == 0) {
    out[row] = sa_ + b3a[0];
    out[12288 + row] = sb_ + b3b[0];
  }
}

// ---------------------------------------------------------------------------
extern "C" void kernel_launch(void* const* d_in, const int* in_sizes, int n_in,
                              void* d_out, int out_size, void* d_ws,
                              size_t ws_size, hipStream_t stream) {
  const float* obs  = (const float*)d_in[0];
  const float* acts = (const float*)d_in[1];
  const float* scan = (const float*)d_in[2];
  const float* cw1  = (const float*)d_in[3];
  const float* cb1  = (const float*)d_in[4];
  const float* cw2  = (const float*)d_in[5];
  const float* cb2  = (const float*)d_in[6];
  const float* fw1  = (const float*)d_in[7];
  const float* fb1  = (const float*)d_in[8];
  const float* fw2  = (const float*)d_in[9];
  const float* fb2  = (const float*)d_in[10];
  const float* encw = (const float*)d_in[11];
  const float* encb = (const float*)d_in[12];
  const float* Wk   = (const float*)d_in[13];
  const float* Wv   = (const float*)d_in[14];
  const float* bv   = (const float*)d_in[15];
  const float* Wq   = (const float*)d_in[16];
  const float* q1w1 = (const float*)d_in[17];
  const float* q1b1 = (const float*)d_in[18];
  const float* q1w2 = (const float*)d_in[19];
  const float* q1b2 = (const float*)d_in[20];
  const float* q1w3 = (const float*)d_in[21];
  const float* q1b3 = (const float*)d_in[22];
  const float* q2w1 = (const float*)d_in[23];
  const float* q2b1 = (const float*)d_in[24];
  const float* q2w2 = (const float*)d_in[25];
  const float* q2b2 = (const float*)d_in[26];
  const float* q2w3 = (const float*)d_in[27];
  const float* q2b3 = (const float*)d_in[28];
  float* out = (float*)d_out;
  char* ws = (char*)d_ws;
  if (ws_size < 60000000u) return;

  u16*   hb    = (u16*)(ws + 0);            // 12288*256 bf16
  float* inps  = (float*)(ws + 6291456);    // 12288*64 f32
  u16*   sab   = (u16*)(ws + 9437184);      // 12288*128 bf16
  u16*   kvqb  = (u16*)(ws + 12582912);     // 3 * 12288*128 bf16
  u16*   embb  = (u16*)(ws + 22020096);     // 12288*256 bf16
  u16*   t1ab  = (u16*)(ws + 28311552);     // 12288*512 bf16
  u16*   t2ab  = (u16*)(ws + 40894464);     // 12288*512 bf16
  u16*   w1b   = (u16*)(ws + 53477376);     // 256*8000 bf16 (permuted)
  float* stats = (float*)(ws + 57573376);   // 256 f32
  u16*   wkvqb = (u16*)(ws + 57574400);     // 640x128 bf16 (Wk;Wv;Wq[3])
  u16*   m1ab  = (u16*)(ws + 57738240);     // 512x256 bf16
  u16*   m2ab  = (u16*)(ws + 58000384);     // 512x256 bf16
  u16*   w2g   = (u16*)(ws + 58262528);     // 32*96 conv2 weights
  u16*   w1g   = (u16*)(ws + 58268672);     // 32*32 conv1 weights (zero-pad)
  float* bc1   = (float*)(ws + 58270720);   // 512 f32
  float* bc2   = (float*)(ws + 58272768);   // 512 f32
  u16*   keysb = kvqb;
  u16*   valsb = kvqb + (size_t)12288 * 128;
  u16*   qb    = kvqb + (size_t)2 * 12288 * 128;

  w1_perm<<<256, 256, 0, stream>>>(fw1, w1b);
  CvtArgs ca;
  const float* srcs[13] = {Wk, Wv, Wq, q1w1, q2w1, q1w2, q2w2, cw2, cw1,
                           q1b1, q2b1, q1b2, q2b2};
  void* dsts[13] = {wkvqb, wkvqb + 16384, wkvqb + 32768, m1ab, m1ab + 65536,
                    m2ab, m2ab + 65536, w2g, w1g, bc1, bc1 + 256, bc2, bc2 + 256};
  const int sz[13] = {16384, 16384, 49152, 65536, 65536, 65536, 65536,
                      3072, 1024, 256, 256, 256, 256};
  const int kinds[13] = {0, 0, 0, 0, 0, 0, 0, 1, 2, 3, 3, 3, 3};
  int cum = 0;
  ca.cum[0] = 0;
  for (int i = 0; i < 13; ++i) {
    ca.src[i] = srcs[i]; ca.dst[i] = dsts[i]; ca.kind[i] = kinds[i];
    cum += sz[i]; ca.cum[i + 1] = cum;
  }
  f2b_multi<<<(cum + 255) / 256, 256, 0, stream>>>(ca, stats);

  mega<<<192, 512, 0, stream>>>(scan, w1g, cb1, w2g, cb2, w1b, fb1, hb);
  fc2_stats<<<384, 256, 0, stream>>>(hb, fw2, fb2, obs, acts, inps, stats);
  enc_kernel<<<384, 256, 0, stream>>>(inps, stats, encw, encb, sab);
  gemm_bt<4, 64><<<dim3(3, 192, 1), 256, 0, stream>>>(
      sab, 128, wkvqb, 128, bv, nullptr, kvqb, 128, 2, 0, 0);
  attn_combine<<<4096, 128, 0, stream>>>(qb, keysb, valsb, sab, embb);
  gemm_bt<1, 64><<<dim3(4, 192, 1), 256, 0, stream>>>(
      embb, 256, m1ab, 256, bc1, nullptr, t1ab, 512, 4, 0, 0);
  gemm_bt<1, 64><<<dim3(4, 192, 1), 256, 0, stream>>>(
      t1ab, 512, m2ab, 256, bc2, nullptr, t2ab, 512, 4, 256, 0);
  final_dot<<<3072, 256, 0, stream>>>(t2ab, q1w3, q1b3, q2w3, q2b3, out);
}

// Round 10
// 357.768 us; speedup vs baseline: 1.2033x; 1.2033x over previous
//
#include <hip/hip_runtime.h>
#include <hip/hip_bf16.h>
#include <cstdint>
#include <cstddef>

typedef unsigned short u16;
typedef __attribute__((ext_vector_type(8))) __bf16 bf16x8;
typedef __attribute__((ext_vector_type(4))) float f32x4;

__device__ __forceinline__ u16 f2b(float f) {
  __hip_bfloat16 h = __float2bfloat16(f);
  return *reinterpret_cast<u16*>(&h);
}
__device__ __forceinline__ uint32_t pk2(float a, float b) {
  __hip_bfloat162 h = __float22bfloat162_rn(make_float2(a, b));
  return *reinterpret_cast<uint32_t*>(&h);
}
__device__ __forceinline__ float b2f(u16 u) {
  union { float f; uint32_t i; } x; x.i = ((uint32_t)u) << 16; return x.f;
}
__device__ __forceinline__ f32x4 mfma16(bf16x8 a, bf16x8 b, f32x4 c) {
  return __builtin_amdgcn_mfma_f32_16x16x32_bf16(a, b, c, 0, 0, 0);
}
__device__ __forceinline__ void async16(const void* g, void* l) {
  __builtin_amdgcn_global_load_lds((const __attribute__((address_space(1))) uint32_t*)g,
                                   (__attribute__((address_space(3))) uint32_t*)l, 16, 0, 0);
}

// ---------------------------------------------------------------------------
// fc_w1 (256x8000) permuted to the conv-epilogue dense-store k-order:
// x element k' = t*32 + c'  with  c2 = ((c'>>2)&1)*16 + (c'>>3)*4 + (c'&3)
__global__ __launch_bounds__(256) void w1_perm(const float* __restrict__ w,
                                               u16* __restrict__ o) {
  __shared__ float L[8000];
  int j = blockIdx.x, tid = threadIdx.x;
  for (int i = tid; i < 8000; i += 256) L[i] = w[(size_t)j * 8000 + i];
  __syncthreads();
  for (int i = tid; i < 8000; i += 256) {
    int tt = i >> 5, cc = i & 31;
    int c2 = ((cc >> 2) & 1) * 16 + (cc >> 3) * 4 + (cc & 3);
    o[(size_t)j * 8000 + i] = f2b(L[c2 * 250 + tt]);
  }
}

struct CvtArgs {
  const float* src[15];
  void* dst[15];
  int cum[16];
  int kind[15];  // 0=f2b copy, 1=w2 permute, 2=w1 zero-pad, 3=float copy
};
__global__ __launch_bounds__(256) void f2b_multi(CvtArgs a, float* stats) {
  int i = blockIdx.x * 256 + threadIdx.x;
  if (blockIdx.x == 0 && threadIdx.x < 128) stats[threadIdx.x] = 0.f;
  int seg = 0;
  #pragma unroll
  for (int s = 1; s < 15; ++s) if (i >= a.cum[s]) seg = s;
  if (i < a.cum[15]) {
    int off = i - a.cum[seg];
    int kind = a.kind[seg];
    const float* src = a.src[seg];
    if (kind == 0) {
      ((u16*)a.dst[seg])[off] = f2b(src[off]);
    } else if (kind == 1) {
      int c2 = off / 96, rem = off - c2 * 96, kk = rem >> 5, c1 = rem & 31;
      ((u16*)a.dst[seg])[off] = f2b(src[(c2 * 32 + c1) * 3 + kk]);
    } else if (kind == 2) {
      int c1 = off >> 5, k = off & 31;
      ((u16*)a.dst[seg])[off] = f2b(k < 5 ? src[c1 * 5 + k] : 0.f);
    } else {
      ((float*)a.dst[seg])[off] = src[off];
    }
  }
}

// ---------------------------------------------------------------------------
// Fused conv1 (bf16 MFMA via 8-wide im2col + zero-quads trick) + conv2 (bf16
// MFMA). One block per scan row, ONE barrier, dense 16B epilogue stores.
// x layout: x[row][t*32 + quad*8 + i*4 + r] (w1_perm matches)
__global__ __launch_bounds__(256) void conv_fused(
    const float* __restrict__ scan, const u16* __restrict__ w1g,
    const float* __restrict__ cb1, const u16* __restrict__ w2g,
    const float* __restrict__ cb2, u16* __restrict__ x) {
  __shared__ __align__(16) u16 A1[256 * 8];    // im2col [p][k<8], 4KB
  __shared__ __align__(16) u16 zbuf[4 * 8];    // per-wave 16B zeros
  __shared__ __align__(16) u16 h1T[258 * 40];  // [p][c1], stride 40
  int tid = threadIdx.x, lane = tid & 63, wv = tid >> 6;
  int l15 = lane & 15, quad = lane >> 4;
  const float* srow = scan + (size_t)blockIdx.x * 256;
  float sv[5];
  #pragma unroll
  for (int k = 0; k < 5; ++k) {
    int p = tid + k;
    sv[k] = (p < 256) ? srow[p] : 0.f;
  }
  union { bf16x8 v; uint32_t d[4]; } pk_;
  pk_.d[0] = pk2(sv[0], sv[1]);
  pk_.d[1] = pk2(sv[2], sv[3]);
  pk_.d[2] = pk2(sv[4], 0.f);
  pk_.d[3] = 0;
  *(bf16x8*)&A1[tid * 8] = pk_.v;
  if (lane < 8) zbuf[wv * 8 + lane] = 0;
  if (tid < 80) h1T[256 * 40 + tid] = 0;  // zero rows 256,257
  bf16x8 w1f[2];
  w1f[0] = *(const bf16x8*)&w1g[l15 * 32 + quad * 8];
  w1f[1] = *(const bf16x8*)&w1g[(16 + l15) * 32 + quad * 8];
  bf16x8 w2f[2][3];
  #pragma unroll
  for (int i = 0; i < 2; ++i)
    #pragma unroll
    for (int kk = 0; kk < 3; ++kk)
      w2f[i][kk] = *(const bf16x8*)&w2g[(i * 16 + l15) * 96 + kk * 32 + quad * 8];
  float cb1v[2][4], cb2v[2][4];
  #pragma unroll
  for (int i = 0; i < 2; ++i)
    #pragma unroll
    for (int r = 0; r < 4; ++r) {
      cb1v[i][r] = cb1[i * 16 + quad * 4 + r];
      cb2v[i][r] = cb2[i * 16 + quad * 4 + r];
    }
  asm volatile("s_waitcnt lgkmcnt(0)" ::: "memory");
  f32x4 zero = {0.f, 0.f, 0.f, 0.f};
  {  // conv1 MFMA: D[c1][p], intra-wave rows p = wv*64..+63
    f32x4 acc1[4][2];
    #pragma unroll
    for (int nt = 0; nt < 4; ++nt) { acc1[nt][0] = zero; acc1[nt][1] = zero; }
    #pragma unroll
    for (int nt = 0; nt < 4; ++nt) {
      int p = (wv * 4 + nt) * 16 + l15;
      const u16* bp = (quad == 0) ? &A1[p * 8] : &zbuf[wv * 8];
      bf16x8 bfr = *(const bf16x8*)bp;
      acc1[nt][0] = mfma16(w1f[0], bfr, acc1[nt][0]);
      acc1[nt][1] = mfma16(w1f[1], bfr, acc1[nt][1]);
    }
    #pragma unroll
    for (int nt = 0; nt < 4; ++nt) {
      int p = (wv * 4 + nt) * 16 + l15;
      #pragma unroll
      for (int mt = 0; mt < 2; ++mt) {
        float v0 = fmaxf(acc1[nt][mt][0] + cb1v[mt][0], 0.f);
        float v1 = fmaxf(acc1[nt][mt][1] + cb1v[mt][1], 0.f);
        float v2 = fmaxf(acc1[nt][mt][2] + cb1v[mt][2], 0.f);
        float v3 = fmaxf(acc1[nt][mt][3] + cb1v[mt][3], 0.f);
        uint2 u; u.x = pk2(v0, v1); u.y = pk2(v2, v3);
        *(uint2*)&h1T[p * 40 + mt * 16 + quad * 4] = u;
      }
    }
  }
  __syncthreads();
  f32x4 acc2[4][2];
  #pragma unroll
  for (int jj = 0; jj < 4; ++jj) { acc2[jj][0] = zero; acc2[jj][1] = zero; }
  #pragma unroll
  for (int kk = 0; kk < 3; ++kk) {
    #pragma unroll
    for (int jj = 0; jj < 4; ++jj) {
      int t = (wv * 4 + jj) * 16 + l15 + kk;
      bf16x8 h = *(const bf16x8*)&h1T[t * 40 + quad * 8];
      acc2[jj][0] = mfma16(w2f[0][kk], h, acc2[jj][0]);
      acc2[jj][1] = mfma16(w2f[1][kk], h, acc2[jj][1]);
    }
  }
  u16* xr = x + (size_t)blockIdx.x * 8000;
  #pragma unroll
  for (int jj = 0; jj < 4; ++jj) {
    int t = (wv * 4 + jj) * 16 + l15;
    if (t < 250) {
      union { bf16x8 v; uint32_t d[4]; } o_;
      #pragma unroll
      for (int i = 0; i < 2; ++i) {
        float v0 = fmaxf(acc2[jj][i][0] + cb2v[i][0], 0.f);
        float v1 = fmaxf(acc2[jj][i][1] + cb2v[i][1], 0.f);
        float v2 = fmaxf(acc2[jj][i][2] + cb2v[i][2], 0.f);
        float v3 = fmaxf(acc2[jj][i][3] + cb2v[i][3], 0.f);
        o_.d[i * 2]     = pk2(v0, v1);
        o_.d[i * 2 + 1] = pk2(v2, v3);
      }
      *(bf16x8*)&xr[t * 32 + quad * 8] = o_.v;
    }
  }
}

// ---------------------------------------------------------------------------
// NT bf16 MFMA GEMM, MROWS x 128 tile, BK=64, dbuf + depth-1 prefetch,
// 8-slot XOR swizzle (0 conflicts). lda/ldw separate.
// MODE 0: fp32 raw split-K. MODE 1: +bias relu bf16. MODE 4: merged KVQ.
// MODE 5: +bias relu then fused final dot vs w3cat -> per-(row, 64-col-half)
//         partials in pd (8 slots x 12288 rows).
template <int MODE, int MROWS>
__global__ __launch_bounds__(256) void gemm_bt(
    const u16* __restrict__ A, int lda, const u16* __restrict__ W, int ldw,
    const float* __restrict__ bias, float* __restrict__ outF,
    u16* __restrict__ outB, int ldo, int nst, int a_sel, size_t out_zoff,
    const float* __restrict__ w3cat, float* __restrict__ pd) {
  constexpr int AI = (MROWS * 8) / 256;
  __shared__ __align__(16) u16 As[2][MROWS * 64];
  __shared__ __align__(16) u16 Bs[2][128 * 64];
  int tid = threadIdx.x;
  int m0 = blockIdx.y * MROWS;
  int sel = (MODE == 4) ? blockIdx.x : 0;
  int n0 = (MODE == 4) ? 0 : blockIdx.x * 128;
  if (MODE == 4) {
    size_t woff = (sel < 2) ? (size_t)sel * 128 : (size_t)(256 + (m0 >> 12) * 128);
    W += woff * 128;
    outB += (size_t)sel * 12288 * 128;
  }
  if (a_sel) A += (size_t)(blockIdx.x >> 1) * a_sel;
  int kbase = blockIdx.z * nst * 64;
  if (MODE == 0) outF += (size_t)blockIdx.z * out_zoff;
  const u16* Ap = A + (size_t)m0 * lda + kbase;
  const u16* Wp = W + (size_t)n0 * ldw + kbase;
  int lane = tid & 63, wv = tid >> 6;
  int l15 = lane & 15, quad = lane >> 4;
  int wm = (wv >> 1) * (MROWS / 2), wn = (wv & 1) * 64;
  constexpr int MI = MROWS / 32;
  f32x4 zero = {0.f, 0.f, 0.f, 0.f};
  f32x4 acc[MI][4];
  #pragma unroll
  for (int i = 0; i < MI; ++i)
    #pragma unroll
    for (int j = 0; j < 4; ++j) acc[i][j] = zero;

  int sraA[AI], sofA[AI], sdsA[AI];
  #pragma unroll
  for (int it = 0; it < AI; ++it) {
    int c = it * 256 + tid;
    int row = c >> 3, slot = c & 7;
    sraA[it] = row;
    sofA[it] = ((slot ^ (row & 7)) * 8);
    sdsA[it] = c * 8;
  }
  int sraW[4], sofW[4], sdsW[4];
  #pragma unroll
  for (int it = 0; it < 4; ++it) {
    int c = it * 256 + tid;
    int row = c >> 3, slot = c & 7;
    sraW[it] = row;
    sofW[it] = ((slot ^ (row & 7)) * 8);
    sdsW[it] = c * 8;
  }
  int rslot[2];
  rslot[0] = ((quad ^ (l15 & 7)) * 8);
  rslot[1] = (((4 + quad) ^ (l15 & 7)) * 8);

  #pragma unroll 1
  for (int st = 0; st < nst; ++st) {
    if (st == 0) {
      #pragma unroll
      for (int it = 0; it < AI; ++it)
        async16(Ap + (size_t)sraA[it] * lda + sofA[it], &As[0][sdsA[it]]);
      #pragma unroll
      for (int it = 0; it < 4; ++it)
        async16(Wp + (size_t)sraW[it] * ldw + sofW[it], &Bs[0][sdsW[it]]);
    }
    __syncthreads();
    if (st + 1 < nst) {
      const u16* An = Ap + (st + 1) * 64;
      const u16* Wn = Wp + (st + 1) * 64;
      u16* Ad = &As[(st + 1) & 1][0];
      u16* Bd = &Bs[(st + 1) & 1][0];
      #pragma unroll
      for (int it = 0; it < AI; ++it)
        async16(An + (size_t)sraA[it] * lda + sofA[it], Ad + sdsA[it]);
      #pragma unroll
      for (int it = 0; it < 4; ++it)
        async16(Wn + (size_t)sraW[it] * ldw + sofW[it], Bd + sdsW[it]);
    }
    const u16* Ab = &As[st & 1][0];
    const u16* Bb = &Bs[st & 1][0];
    #pragma unroll
    for (int s = 0; s < 2; ++s) {
      bf16x8 af[MI], bfr[4];
      #pragma unroll
      for (int i = 0; i < MI; ++i)
        af[i] = *(const bf16x8*)&Ab[(wm + i * 16 + l15) * 64 + rslot[s]];
      #pragma unroll
      for (int j = 0; j < 4; ++j)
        bfr[j] = *(const bf16x8*)&Bb[(wn + j * 16 + l15) * 64 + rslot[s]];
      #pragma unroll
      for (int i = 0; i < MI; ++i)
        #pragma unroll
        for (int j = 0; j < 4; ++j) acc[i][j] = mfma16(af[i], bfr[j], acc[i][j]);
    }
  }
  if (MODE == 5) {
    float w3v[4], bv4[4];
    #pragma unroll
    for (int j = 0; j < 4; ++j) {
      int n = n0 + wn + j * 16 + l15;
      w3v[j] = w3cat[n];
      bv4[j] = bias[n];
    }
    int sblk = (n0 >> 7) * 2 + (wv & 1);
    #pragma unroll
    for (int i = 0; i < MI; ++i) {
      int mb = m0 + wm + i * 16 + quad * 4;
      #pragma unroll
      for (int r = 0; r < 4; ++r) {
        float s = 0.f;
        #pragma unroll
        for (int j = 0; j < 4; ++j) {
          float v = fmaxf(acc[i][j][r] + bv4[j], 0.f);
          s += v * w3v[j];
        }
        s += __shfl_down(s, 8);
        s += __shfl_down(s, 4);
        s += __shfl_down(s, 2);
        s += __shfl_down(s, 1);
        if (l15 == 0) pd[(size_t)sblk * 12288 + mb + r] = s;
      }
    }
    return;
  }
  #pragma unroll
  for (int i = 0; i < MI; ++i) {
    int mb = m0 + wm + i * 16 + quad * 4;
    #pragma unroll
    for (int j = 0; j < 4; ++j) {
      int n = n0 + wn + j * 16 + l15;
      float bv_ = (MODE == 1 || MODE == 4) ? bias[n] : 0.f;
      #pragma unroll
      for (int r = 0; r < 4; ++r) {
        float v = acc[i][j][r];
        if (MODE == 0) {
          outF[(size_t)(mb + r) * ldo + n] = v;
        } else if (MODE == 1) {
          v = fmaxf(v + bv_, 0.f);
          outB[(size_t)(mb + r) * ldo + n] = f2b(v);
        } else {
          if (sel == 1) { v += bv_; v = v >= 0.f ? v : 0.01f * v; }
          outB[(size_t)(mb + r) * ldo + n] = f2b(v);
        }
      }
    }
  }
}

// ---------------------------------------------------------------------------
// fc2 (relu(sum hparts + b1) @ w2^T + b2) + build inps rows + batch-stat partials
__global__ __launch_bounds__(256) void fc2_stats(
    const float* __restrict__ hparts, const float* __restrict__ b1,
    const float* __restrict__ w2, const float* __restrict__ b2,
    const float* __restrict__ obs, const float* __restrict__ acts,
    float* __restrict__ inps, float* __restrict__ stats) {
  __shared__ float hL[32 * 260];
  __shared__ float w2L[10 * 260];
  __shared__ float b1L[256];
  __shared__ float ipL[32 * 61];
  int tid = threadIdx.x, r0 = blockIdx.x * 32;
  b1L[tid] = b1[tid];
  for (int i = tid; i < 2560; i += 256) w2L[(i >> 8) * 260 + (i & 255)] = w2[i];
  for (int i = tid; i < 32 * 48; i += 256) {
    int r = i / 48, f = i - r * 48;
    ipL[r * 61 + f] = obs[(size_t)(r0 + r) * 48 + f];
  }
  if (tid < 64) {
    int r = tid >> 1, f = tid & 1;
    ipL[r * 61 + 48 + f] = acts[(size_t)(r0 + r) * 2 + f];
  }
  __syncthreads();
  const size_t HS = (size_t)12288 * 256;
  for (int i = tid; i < 32 * 256; i += 256) {
    int r = i >> 8, c = i & 255;
    size_t g = (size_t)(r0 + r) * 256 + c;
    float v = b1L[c] + hparts[g] + hparts[g + HS] + hparts[g + 2 * HS] +
              hparts[g + 3 * HS] + hparts[g + 4 * HS];
    hL[r * 260 + c] = fmaxf(v, 0.f);
  }
  __syncthreads();
  {
    int r = tid >> 3, ob = tid & 7;
    for (int o = ob; o < 10; o += 8) {
      float a = 0.f;
      #pragma unroll 8
      for (int c = 0; c < 256; ++c) a += hL[r * 260 + c] * w2L[o * 260 + c];
      ipL[r * 61 + 50 + o] = a + b2[o];
    }
  }
  __syncthreads();
  for (int i = tid; i < 32 * 60; i += 256) {
    int r = i / 60, f = i - r * 60;
    inps[(size_t)(r0 + r) * 64 + f] = ipL[r * 61 + f];
  }
  if (tid < 60) {
    float s = 0.f, s2 = 0.f;
    for (int r = 0; r < 32; ++r) {
      float v = ipL[r * 61 + tid];
      s += v; s2 += v * v;
    }
    atomicAdd(&stats[tid], s);
    atomicAdd(&stats[64 + tid], s2);
  }
}

// ---------------------------------------------------------------------------
// normalize + enc (60->128) + leaky -> sa (bf16)
__global__ __launch_bounds__(256) void enc_kernel(
    const float* __restrict__ inps, const float* __restrict__ stats,
    const float* __restrict__ enc_w, const float* __restrict__ enc_b,
    u16* __restrict__ sab) {
  __shared__ float ewL[128 * 61];
  __shared__ float nrm[32 * 61];
  __shared__ float ebL[128];
  __shared__ float muL[60], ivL[60];
  int tid = threadIdx.x, r0 = blockIdx.x * 32;
  if (tid < 128) ebL[tid] = enc_b[tid];
  if (tid < 60) {
    float s = stats[tid], s2 = stats[64 + tid];
    float mu = s * (1.f / 12288.f);
    float var = s2 * (1.f / 12288.f) - mu * mu;
    muL[tid] = mu;
    ivL[tid] = rsqrtf(var + 1e-5f);
  }
  for (int i = tid; i < 128 * 60; i += 256) {
    int h = i / 60, f = i - h * 60;
    ewL[h * 61 + f] = enc_w[i];
  }
  __syncthreads();
  for (int i = tid; i < 32 * 60; i += 256) {
    int r = i / 60, f = i - r * 60;
    nrm[r * 61 + f] = (inps[(size_t)(r0 + r) * 64 + f] - muL[f]) * ivL[f];
  }
  __syncthreads();
  for (int i = tid; i < 32 * 128; i += 256) {
    int r = i >> 7, h = i & 127;
    float a = ebL[h];
    #pragma unroll 4
    for (int f = 0; f < 60; ++f) a += nrm[r * 61 + f] * ewL[h * 61 + f];
    a = a >= 0.f ? a : 0.01f * a;
    sab[(size_t)(r0 + r) * 128 + h] = f2b(a);
  }
}

// ---------------------------------------------------------------------------
// attention combine: per-b softmax over other agents + emb = [sa | other] (bf16)
__global__ __launch_bounds__(128) void attn_combine(
    const u16* __restrict__ qb, const u16* __restrict__ keysb,
    const u16* __restrict__ valsb, const u16* __restrict__ sab,
    u16* __restrict__ emb) {
  __shared__ float qL[3][128], kL[3][128], vL[3][128];
  __shared__ float lg[3][8][3], wgt[3][8][3];
  int b = blockIdx.x, t = threadIdx.x;
  #pragma unroll
  for (int o = 0; o < 3; ++o) {
    size_t base = (size_t)(o * 4096 + b) * 128 + t;
    qL[o][t] = b2f(qb[base]);
    kL[o][t] = b2f(keysb[base]);
    vL[o][t] = b2f(valsb[base]);
  }
  __syncthreads();
  if (t < 72) {
    int g = t / 24, n = (t / 3) % 8, o = t % 3;
    float a = 0.f;
    #pragma unroll
    for (int d = 0; d < 16; ++d) a += qL[g][n * 16 + d] * kL[o][n * 16 + d];
    lg[g][n][o] = (o == g) ? -1e30f : a * 0.25f;
  }
  __syncthreads();
  if (t < 24) {
    int g = t / 8, n = t % 8;
    float m = fmaxf(fmaxf(lg[g][n][0], lg[g][n][1]), lg[g][n][2]);
    float e0 = expf(lg[g][n][0] - m), e1 = expf(lg[g][n][1] - m),
          e2 = expf(lg[g][n][2] - m);
    float inv = 1.f / (e0 + e1 + e2);
    wgt[g][n][0] = e0 * inv; wgt[g][n][1] = e1 * inv; wgt[g][n][2] = e2 * inv;
  }
  __syncthreads();
  int n = t >> 4, d = t & 15;
  #pragma unroll
  for (int g = 0; g < 3; ++g) {
    float o_ = wgt[g][n][0] * vL[0][n * 16 + d] +
               wgt[g][n][1] * vL[1][n * 16 + d] +
               wgt[g][n][2] * vL[2][n * 16 + d];
    size_t rbase = (size_t)(g * 4096 + b) * 256;
    emb[rbase + 128 + t] = f2b(o_);
    emb[rbase + t] = sab[(size_t)(g * 4096 + b) * 128 + t];
  }
}

// ---------------------------------------------------------------------------
// sum 4 partials per head per row + bias
__global__ __launch_bounds__(256) void final_sum(
    const float* __restrict__ pd, const float* __restrict__ b3a,
    const float* __restrict__ b3b, float* __restrict__ out) {
  int row = blockIdx.x * 256 + threadIdx.x;
  const size_t R = 12288;
  float s1 = pd[row] + pd[R + row] + pd[2 * R + row] + pd[3 * R + row];
  float s2 = pd[4 * R + row] + pd[5 * R + row] + pd[6 * R + row] + pd[7 * R + row];
  out[row] = s1 + b3a[0];
  out[R + row] = s2 + b3b[0];
}

// ---------------------------------------------------------------------------
extern "C" void kernel_launch(void* const* d_in, const int* in_sizes, int n_in,
                              void* d_out, int out_size, void* d_ws,
                              size_t ws_size, hipStream_t stream) {
  const float* obs  = (const float*)d_in[0];
  const float* acts = (const float*)d_in[1];
  const float* scan = (const float*)d_in[2];
  const float* cw1  = (const float*)d_in[3];
  const float* cb1  = (const float*)d_in[4];
  const float* cw2  = (const float*)d_in[5];
  const float* cb2  = (const float*)d_in[6];
  const float* fw1  = (const float*)d_in[7];
  const float* fb1  = (const float*)d_in[8];
  const float* fw2  = (const float*)d_in[9];
  const float* fb2  = (const float*)d_in[10];
  const float* encw = (const float*)d_in[11];
  const float* encb = (const float*)d_in[12];
  const float* Wk   = (const float*)d_in[13];
  const float* Wv   = (const float*)d_in[14];
  const float* bv   = (const float*)d_in[15];
  const float* Wq   = (const float*)d_in[16];
  const float* q1w1 = (const float*)d_in[17];
  const float* q1b1 = (const float*)d_in[18];
  const float* q1w2 = (const float*)d_in[19];
  const float* q1b2 = (const float*)d_in[20];
  const float* q1w3 = (const float*)d_in[21];
  const float* q1b3 = (const float*)d_in[22];
  const float* q2w1 = (const float*)d_in[23];
  const float* q2b1 = (const float*)d_in[24];
  const float* q2w2 = (const float*)d_in[25];
  const float* q2b2 = (const float*)d_in[26];
  const float* q2w3 = (const float*)d_in[27];
  const float* q2b3 = (const float*)d_in[28];
  float* out = (float*)d_out;
  char* ws = (char*)d_ws;
  if (ws_size < 264400000u) return;

  // persistent region
  u16*   x     = (u16*)(ws + 0);            // 12288*8000 bf16
  u16*   w1b   = (u16*)(ws + 196608000);    // 256*8000 bf16 (permuted)
  float* hpart = (float*)(ws + 200704000);  // 5 * 12288*256 fp32
  float* stats = (float*)(ws + 263618560);  // 256 f32
  u16*   wkvqb = (u16*)(ws + 263619584);    // 640x128 bf16 (Wk;Wv;Wq[3])
  u16*   m1ab  = (u16*)(ws + 263783424);    // 512x256 bf16 (q1w1;q2w1)
  u16*   m2ab  = (u16*)(ws + 264045568);    // 512x256 bf16 (q1w2;q2w2)
  u16*   w2g   = (u16*)(ws + 264307712);    // 32*96 conv2 weights
  u16*   w1g   = (u16*)(ws + 264313856);    // 32*32 conv1 weights (zero-pad)
  float* bc1   = (float*)(ws + 264315904);  // 512 f32
  float* bc2   = (float*)(ws + 264317952);  // 512 f32
  float* w3cat = (float*)(ws + 264320000);  // 512 f32 (q1w3;q2w3)
  // phase-2 aliases over x (dead after fc1 GEMM)
  float* inps  = (float*)(ws + 0);          // 12288*64 f32
  u16*   sab   = (u16*)(ws + 3145728);      // 12288*128 bf16
  u16*   kvqb  = (u16*)(ws + 6291456);      // 3 * 12288*128 bf16 (K;V;Q)
  u16*   embb  = (u16*)(ws + 15728640);     // 12288*256 bf16
  u16*   t1ab  = (u16*)(ws + 22020096);     // 12288*512 bf16
  float* pd    = (float*)(ws + 34603008);   // 8 * 12288 f32 partials
  u16*   keysb = kvqb;
  u16*   valsb = kvqb + (size_t)12288 * 128;
  u16*   qb    = kvqb + (size_t)2 * 12288 * 128;

  w1_perm<<<256, 256, 0, stream>>>(fw1, w1b);
  CvtArgs ca;
  const float* srcs[15] = {Wk, Wv, Wq, q1w1, q2w1, q1w2, q2w2, cw2, cw1,
                           q1b1, q2b1, q1b2, q2b2, q1w3, q2w3};
  void* dsts[15] = {wkvqb, wkvqb + 16384, wkvqb + 32768, m1ab, m1ab + 65536,
                    m2ab, m2ab + 65536, w2g, w1g, bc1, bc1 + 256, bc2,
                    bc2 + 256, w3cat, w3cat + 256};
  const int sz[15] = {16384, 16384, 49152, 65536, 65536, 65536, 65536,
                      3072, 1024, 256, 256, 256, 256, 256, 256};
  const int kinds[15] = {0, 0, 0, 0, 0, 0, 0, 1, 2, 3, 3, 3, 3, 3, 3};
  int cum = 0;
  ca.cum[0] = 0;
  for (int i = 0; i < 15; ++i) {
    ca.src[i] = srcs[i]; ca.dst[i] = dsts[i]; ca.kind[i] = kinds[i];
    cum += sz[i]; ca.cum[i + 1] = cum;
  }
  f2b_multi<<<(cum + 255) / 256, 256, 0, stream>>>(ca, stats);

  conv_fused<<<12288, 256, 0, stream>>>(scan, w1g, cb1, w2g, cb2, x);
  gemm_bt<0, 128><<<dim3(2, 96, 5), 256, 0, stream>>>(
      x, 8000, w1b, 8000, nullptr, hpart, nullptr, 256, 25, 0,
      (size_t)12288 * 256, nullptr, nullptr);
  fc2_stats<<<384, 256, 0, stream>>>(hpart, fb1, fw2, fb2, obs, acts, inps, stats);
  enc_kernel<<<384, 256, 0, stream>>>(inps, stats, encw, encb, sab);
  gemm_bt<4, 64><<<dim3(3, 192, 1), 256, 0, stream>>>(
      sab, 128, wkvqb, 128, bv, nullptr, kvqb, 128, 2, 0, 0, nullptr, nullptr);
  attn_combine<<<4096, 128, 0, stream>>>(qb, keysb, valsb, sab, embb);
  gemm_bt<1, 64><<<dim3(4, 192, 1), 256, 0, stream>>>(
      embb, 256, m1ab, 256, bc1, nullptr, t1ab, 512, 4, 0, 0, nullptr, nullptr);
  gemm_bt<5, 64><<<dim3(4, 192, 1), 256, 0, stream>>>(
      t1ab, 512, m2ab, 256, bc2, nullptr, nullptr, 0, 4, 256, 0, w3cat, pd);
  final_sum<<<48, 256, 0, stream>>>(pd, q1b3, q2b3, out);
}